// Round 10
// baseline (1127.163 us; speedup 1.0000x reference)
//
#include <hip/hip_runtime.h>

// Dims: x[b=32][i=2048][n=16], W[j=64][i=2048][m=32][n=16], bias[j=64][m=32], out v[b=32][j=64][m=32]
// MFMA shape 32x32x16: M=m(32), N=b(32), K=n(16).
//   accum: fp32 -> bf16 hi/lo split, 3 MFMAs (precision path).
//   stats: pure bf16 hi, 1 MFMA (feeds softmax only; 0.2% c-error -> ~1e-4 in s).
// A frag: lane l holds W[j,i, m=l&31, n=(l>>5)*8+e]; B frag: x[b=l&31, i, n=(l>>5)*8+e]
// C/D:    lane l, reg r = u_hat[b=l&31][m=(r&3)+8*(r>>2)+4*(l>>5)]   (m74/m101-verified)
// ws: sbuf[65536] + Zinv[65536] + counter (524,292 B). ws >= 768 KB established r1-r3.
// Grid 512 = 2 blocks/CU, 512-thr blocks (VGPR cap 256, no spill; r6 lesson).
// squash fused into accum via last-block-done (saves 3 launches + gaps).
constexpr float FEPS = 1e-8f;

typedef __attribute__((ext_vector_type(8)))  short bf16x8;
typedef __attribute__((ext_vector_type(16))) float f32x16;

__device__ __forceinline__ short bf16_rne(float f) {
    unsigned u = __float_as_uint(f);
    return (short)((u + 0x7FFFu + ((u >> 16) & 1u)) >> 16);
}
__device__ __forceinline__ float bf16_val(short h) {
    return __uint_as_float(((unsigned)(unsigned short)h) << 16);
}
__device__ __forceinline__ void cvt8(const float4 a, const float4 b, bf16x8& hi, bf16x8& lo) {
    float v[8] = {a.x, a.y, a.z, a.w, b.x, b.y, b.z, b.w};
    #pragma unroll
    for (int e = 0; e < 8; ++e) {
        const short hb = bf16_rne(v[e]);
        hi[e] = hb;
        lo[e] = bf16_rne(v[e] - bf16_val(hb));
    }
}
__device__ __forceinline__ bf16x8 cvt8hi(const float4 a, const float4 b) {
    float v[8] = {a.x, a.y, a.z, a.w, b.x, b.y, b.z, b.w};
    bf16x8 hi;
    #pragma unroll
    for (int e = 0; e < 8; ++e) hi[e] = bf16_rne(v[e]);
    return hi;
}
#define MFMA(A, B, C) __builtin_amdgcn_mfma_f32_32x32x16_bf16((A), (B), (C), 0, 0, 0)

// ---------------------------------------------------------------------------
// stats: Zinv[b,i] = 1 / sum_j exp(veff[b,j,:] . u_hat_bf16[b,j,i,:])
// grid 512 = 4-i slab; 512 thr = 8 waves; wave w covers j in {w, w+8, .., w+56}, all 4 i.
__global__ __launch_bounds__(512, 2)
void stats_pass(const float* __restrict__ W, const float* __restrict__ x,
                const float* __restrict__ veff, float* __restrict__ Zinv)
{
    __shared__ float zred[8][32][5];          // [wave][b][ii] (+1 pad)
    const int tid = threadIdx.x;
    const int l = tid & 63, w = tid >> 6;     // w = 0..7
    const int b = l & 31, h = l >> 5;
    const int i0 = blockIdx.x * 4;

    bf16x8 xh[4];
    #pragma unroll
    for (int ii = 0; ii < 4; ++ii) {
        const float* xr = x + (((size_t)b << 15) + ((size_t)(i0 + ii) << 4) + (h << 3));
        xh[ii] = cvt8hi(*(const float4*)xr, *(const float4*)(xr + 4));
    }
    float zacc[4] = {0.f, 0.f, 0.f, 0.f};

    #pragma unroll 1
    for (int jt = 0; jt < 8; ++jt) {
        const int j = w + (jt << 3);
        const float* vr = veff + ((((size_t)b << 6) | (size_t)j) << 5) + (h << 2);
        const float4 vq0 = *(const float4*)(vr + 0);
        const float4 vq1 = *(const float4*)(vr + 8);
        const float4 vq2 = *(const float4*)(vr + 16);
        const float4 vq3 = *(const float4*)(vr + 24);
        const float* wrow = W + (((size_t)j << 20) + ((size_t)i0 << 9) + (b << 4) + (h << 3));
        #pragma unroll
        for (int ii = 0; ii < 4; ++ii) {
            const bf16x8 wh = cvt8hi(*(const float4*)wrow, *(const float4*)(wrow + 4));
            wrow += 512;
            f32x16 u;
            #pragma unroll
            for (int r = 0; r < 16; ++r) u[r] = 0.f;
            u = MFMA(wh, xh[ii], u);
            float th = 0.f;
            th = fmaf(u[0],  vq0.x, th); th = fmaf(u[1],  vq0.y, th);
            th = fmaf(u[2],  vq0.z, th); th = fmaf(u[3],  vq0.w, th);
            th = fmaf(u[4],  vq1.x, th); th = fmaf(u[5],  vq1.y, th);
            th = fmaf(u[6],  vq1.z, th); th = fmaf(u[7],  vq1.w, th);
            th = fmaf(u[8],  vq2.x, th); th = fmaf(u[9],  vq2.y, th);
            th = fmaf(u[10], vq2.z, th); th = fmaf(u[11], vq2.w, th);
            th = fmaf(u[12], vq3.x, th); th = fmaf(u[13], vq3.y, th);
            th = fmaf(u[14], vq3.z, th); th = fmaf(u[15], vq3.w, th);
            const float t = th + __shfl_xor(th, 32, 64);   // both m-halves
            zacc[ii] += __expf(t);
        }
    }
    if (h == 0) {
        #pragma unroll
        for (int ii = 0; ii < 4; ++ii) zred[w][b][ii] = zacc[ii];
    }
    __syncthreads();
    if (tid < 128) {
        const int bb = tid >> 2, ii = tid & 3;
        float z = 0.f;
        #pragma unroll
        for (int ww = 0; ww < 8; ++ww) z += zred[ww][bb][ii];
        Zinv[((size_t)bb << 11) + i0 + ii] = 1.0f / z;
    }
}

// ---------------------------------------------------------------------------
// accum: s[b,j,:] += sum_i c[b,i,j] * u_hat[b,j,i,:]; last block also squashes:
// v = squash(s + bias) (+ vold), zeroes sbuf, resets counter.
// grid 512 = (j<<3)|iq; 512 thr = 8 waves; wave w owns i in [iq*256 + w*32, +32), all 32 b.
template<int MODE, bool ADDOLD>
__global__ __launch_bounds__(512, 2)
void accum_pass(const float* __restrict__ W, const float* __restrict__ x,
                const float* __restrict__ veff, const float* __restrict__ Zinv,
                float* __restrict__ sbuf, const float* __restrict__ bias,
                float* __restrict__ vout, const float* __restrict__ vold,
                int* __restrict__ counter)
{
    __shared__ float sred[8][32][36];         // [wave][b][m] (+4 pad)
    __shared__ int lastFlag;
    const int tid = threadIdx.x;
    const int l = tid & 63, w = tid >> 6;     // w = 0..7
    const int b = l & 31, h = l >> 5;
    const int j  = blockIdx.x >> 3;
    const int iq = blockIdx.x & 7;
    const int ibase = iq * 256 + w * 32;

    float4 vq0, vq1, vq2, vq3;
    if (MODE) {
        const float* vr = veff + ((((size_t)b << 6) | (size_t)j) << 5) + (h << 2);
        vq0 = *(const float4*)(vr + 0);
        vq1 = *(const float4*)(vr + 8);
        vq2 = *(const float4*)(vr + 16);
        vq3 = *(const float4*)(vr + 24);
    }
    f32x16 accs;
    #pragma unroll
    for (int r = 0; r < 16; ++r) accs[r] = 0.f;

    const float* wrow = W + (((size_t)j << 20) + ((size_t)ibase << 9) + (b << 4) + (h << 3));
    #pragma unroll 2
    for (int ii = 0; ii < 32; ++ii) {
        const int i = ibase + ii;
        const float* xr = x + (((size_t)b << 15) + ((size_t)i << 4) + (h << 3));
        bf16x8 xh, xl, wh, wl;
        cvt8(*(const float4*)xr, *(const float4*)(xr + 4), xh, xl);
        cvt8(*(const float4*)wrow, *(const float4*)(wrow + 4), wh, wl);
        wrow += 512;
        if (MODE == 0) {
            accs = MFMA(wh, xh, accs);
            accs = MFMA(wh, xl, accs);
            accs = MFMA(wl, xh, accs);
        } else {
            f32x16 u;
            #pragma unroll
            for (int r = 0; r < 16; ++r) u[r] = 0.f;
            u = MFMA(wh, xh, u);
            u = MFMA(wh, xl, u);
            u = MFMA(wl, xh, u);
            float th = 0.f;
            th = fmaf(u[0],  vq0.x, th); th = fmaf(u[1],  vq0.y, th);
            th = fmaf(u[2],  vq0.z, th); th = fmaf(u[3],  vq0.w, th);
            th = fmaf(u[4],  vq1.x, th); th = fmaf(u[5],  vq1.y, th);
            th = fmaf(u[6],  vq1.z, th); th = fmaf(u[7],  vq1.w, th);
            th = fmaf(u[8],  vq2.x, th); th = fmaf(u[9],  vq2.y, th);
            th = fmaf(u[10], vq2.z, th); th = fmaf(u[11], vq2.w, th);
            th = fmaf(u[12], vq3.x, th); th = fmaf(u[13], vq3.y, th);
            th = fmaf(u[14], vq3.z, th); th = fmaf(u[15], vq3.w, th);
            const float t = th + __shfl_xor(th, 32, 64);
            const float c = __expf(t) * Zinv[((size_t)b << 11) + i];
            #pragma unroll
            for (int r = 0; r < 16; ++r) accs[r] = fmaf(c, u[r], accs[r]);
        }
    }
    const float scale = (MODE == 0) ? 0.015625f : 1.0f;
    #pragma unroll
    for (int q = 0; q < 4; ++q) {
        *(float4*)&sred[w][b][q * 8 + (h << 2)] =
            make_float4(accs[q*4] * scale, accs[q*4+1] * scale,
                        accs[q*4+2] * scale, accs[q*4+3] * scale);
    }
    __syncthreads();
    #pragma unroll
    for (int k = 0; k < 2; ++k) {
        const int idx = tid * 2 + k;
        const int bb = idx >> 5, mm = idx & 31;
        float s = 0.f;
        #pragma unroll
        for (int ww = 0; ww < 8; ++ww) s += sred[ww][bb][mm];
        atomicAdd(sbuf + ((((size_t)bb << 6) | (size_t)j) << 5) + mm, s);
    }

    // ---- last-block-done: fused squash ----
    __threadfence();                          // make my atomics visible before counting
    if (tid == 0)
        lastFlag = (atomicAdd(counter, 1) == (int)gridDim.x - 1);
    __syncthreads();
    if (!lastFlag) return;
    __threadfence();                          // acquire: all blocks' atomics visible
    const int m = tid & 31, g = tid >> 5;     // 16 groups of 32 lanes (lane = m)
    for (int pair = g; pair < 2048; pair += 16) {  // pair = b*64 + j
        const int jj = pair & 63;
        const size_t idx = ((size_t)pair << 5) + m;
        float s = __hip_atomic_load(&sbuf[idx], __ATOMIC_RELAXED, __HIP_MEMORY_SCOPE_AGENT)
                + bias[(jj << 5) + m];
        sbuf[idx] = 0.f;                      // re-arm for next accum pass
        float n2 = s * s;
        n2 += __shfl_xor(n2, 1, 64);  n2 += __shfl_xor(n2, 2, 64);
        n2 += __shfl_xor(n2, 4, 64);  n2 += __shfl_xor(n2, 8, 64);
        n2 += __shfl_xor(n2, 16, 64);         // xors <=16 stay within each 32-lane half
        float v = s * (n2 / (1.f + n2)) / sqrtf(n2 + FEPS);
        if (ADDOLD) v += vold[idx];
        vout[idx] = v;
    }
    if (tid == 0) *counter = 0;               // deterministic reset for next pass/replay
}

extern "C" void kernel_launch(void* const* d_in, const int* in_sizes, int n_in,
                              void* d_out, int out_size, void* d_ws, size_t ws_size,
                              hipStream_t stream)
{
    const float* x    = (const float*)d_in[0];
    const float* W    = (const float*)d_in[1];
    const float* bias = (const float*)d_in[2];
    float* out  = (float*)d_out;              // running veff lives here
    float* sbuf = (float*)d_ws;               // 65536 floats
    float* Zinv = sbuf + 65536;               // 65536 floats
    int*   ctr  = (int*)(sbuf + 131072);      // 1 int

    // zero sbuf + Zinv + counter (first-call poison; later passes self-re-arm)
    hipMemsetAsync(d_ws, 0, 131073 * sizeof(float), stream);

    // it0: c = 1/64 exactly -> out = v0
    accum_pass<0, false><<<512, 512, 0, stream>>>(W, x, nullptr, nullptr, sbuf, bias, out, nullptr, ctr);
    // it1: Z from veff=v0; out = v0 + v1
    stats_pass<<<512, 512, 0, stream>>>(W, x, out, Zinv);
    accum_pass<1, true ><<<512, 512, 0, stream>>>(W, x, out, Zinv, sbuf, bias, out, out, ctr);
    // it2: Z from veff=v0+v1; out = v2 (final)
    stats_pass<<<512, 512, 0, stream>>>(W, x, out, Zinv);
    accum_pass<1, false><<<512, 512, 0, stream>>>(W, x, out, Zinv, sbuf, bias, out, nullptr, ctr);
}

// Round 11
// 306.510 us; speedup vs baseline: 3.6774x; 3.6774x over previous
//
#include <hip/hip_runtime.h>

// Dims: x[b=32][i=2048][n=16], W[j=64][i=2048][m=32][n=16], bias[j=64][m=32], out v[b=32][j=64][m=32]
// MFMA shape 32x32x16: M=m(32), N=b(32), K=n(16).
//   stats: pure bf16 hi, 1 MFMA (feeds softmax only — validated r10, absmax unchanged).
//   accum it0/it1 (PREC=0): W hi-only, x hi/lo -> 2 MFMAs (routing-weight passes, error 2nd-order).
//   accum it2     (PREC=1): full hi/lo split -> 3 MFMAs (output-critical pass).
// A frag: lane l holds W[j,i, m=l&31, n=(l>>5)*8+e]; B frag: x[b=l&31, i, n=(l>>5)*8+e]
// C/D:    lane l, reg r = u_hat[b=l&31][m=(r&3)+8*(r>>2)+4*(l>>5)]   (m74/m101-verified)
// ws: sbuf[65536] + Zinv[65536] (512 KB; >= 768 KB established r1-r3).
// Grid 512 = 2 blocks/CU, 512-thr blocks. NO fused tails (r10: tail code -> VGPR-32 spill cliff).
constexpr float FEPS = 1e-8f;

typedef __attribute__((ext_vector_type(8)))  short bf16x8;
typedef __attribute__((ext_vector_type(16))) float f32x16;

__device__ __forceinline__ short bf16_rne(float f) {
    unsigned u = __float_as_uint(f);
    return (short)((u + 0x7FFFu + ((u >> 16) & 1u)) >> 16);
}
__device__ __forceinline__ float bf16_val(short h) {
    return __uint_as_float(((unsigned)(unsigned short)h) << 16);
}
__device__ __forceinline__ void cvt8(const float4 a, const float4 b, bf16x8& hi, bf16x8& lo) {
    float v[8] = {a.x, a.y, a.z, a.w, b.x, b.y, b.z, b.w};
    #pragma unroll
    for (int e = 0; e < 8; ++e) {
        const short hb = bf16_rne(v[e]);
        hi[e] = hb;
        lo[e] = bf16_rne(v[e] - bf16_val(hb));
    }
}
__device__ __forceinline__ bf16x8 cvt8hi(const float4 a, const float4 b) {
    float v[8] = {a.x, a.y, a.z, a.w, b.x, b.y, b.z, b.w};
    bf16x8 hi;
    #pragma unroll
    for (int e = 0; e < 8; ++e) hi[e] = bf16_rne(v[e]);
    return hi;
}
#define MFMA(A, B, C) __builtin_amdgcn_mfma_f32_32x32x16_bf16((A), (B), (C), 0, 0, 0)

// ---------------------------------------------------------------------------
// stats: Zinv[b,i] = 1 / sum_j exp(veff[b,j,:] . u_hat_bf16[b,j,i,:])
// grid 512 = 4-i slab; 512 thr = 8 waves; wave w covers j in {w, w+8, .., w+56}, all 4 i.
__global__ __launch_bounds__(512, 2)
void stats_pass(const float* __restrict__ W, const float* __restrict__ x,
                const float* __restrict__ veff, float* __restrict__ Zinv)
{
    __shared__ float zred[8][32][5];          // [wave][b][ii] (+1 pad)
    const int tid = threadIdx.x;
    const int l = tid & 63, w = tid >> 6;     // w = 0..7
    const int b = l & 31, h = l >> 5;
    const int i0 = blockIdx.x * 4;

    bf16x8 xh[4];
    #pragma unroll
    for (int ii = 0; ii < 4; ++ii) {
        const float* xr = x + (((size_t)b << 15) + ((size_t)(i0 + ii) << 4) + (h << 3));
        xh[ii] = cvt8hi(*(const float4*)xr, *(const float4*)(xr + 4));
    }
    float zacc[4] = {0.f, 0.f, 0.f, 0.f};

    #pragma unroll 1
    for (int jt = 0; jt < 8; ++jt) {
        const int j = w + (jt << 3);
        const float* vr = veff + ((((size_t)b << 6) | (size_t)j) << 5) + (h << 2);
        const float4 vq0 = *(const float4*)(vr + 0);
        const float4 vq1 = *(const float4*)(vr + 8);
        const float4 vq2 = *(const float4*)(vr + 16);
        const float4 vq3 = *(const float4*)(vr + 24);
        const float* wrow = W + (((size_t)j << 20) + ((size_t)i0 << 9) + (b << 4) + (h << 3));
        #pragma unroll
        for (int ii = 0; ii < 4; ++ii) {
            const bf16x8 wh = cvt8hi(*(const float4*)wrow, *(const float4*)(wrow + 4));
            wrow += 512;
            f32x16 u;
            #pragma unroll
            for (int r = 0; r < 16; ++r) u[r] = 0.f;
            u = MFMA(wh, xh[ii], u);
            float th = 0.f;
            th = fmaf(u[0],  vq0.x, th); th = fmaf(u[1],  vq0.y, th);
            th = fmaf(u[2],  vq0.z, th); th = fmaf(u[3],  vq0.w, th);
            th = fmaf(u[4],  vq1.x, th); th = fmaf(u[5],  vq1.y, th);
            th = fmaf(u[6],  vq1.z, th); th = fmaf(u[7],  vq1.w, th);
            th = fmaf(u[8],  vq2.x, th); th = fmaf(u[9],  vq2.y, th);
            th = fmaf(u[10], vq2.z, th); th = fmaf(u[11], vq2.w, th);
            th = fmaf(u[12], vq3.x, th); th = fmaf(u[13], vq3.y, th);
            th = fmaf(u[14], vq3.z, th); th = fmaf(u[15], vq3.w, th);
            const float t = th + __shfl_xor(th, 32, 64);   // both m-halves
            zacc[ii] += __expf(t);
        }
    }
    if (h == 0) {
        #pragma unroll
        for (int ii = 0; ii < 4; ++ii) zred[w][b][ii] = zacc[ii];
    }
    __syncthreads();
    if (tid < 128) {
        const int bb = tid >> 2, ii = tid & 3;
        float z = 0.f;
        #pragma unroll
        for (int ww = 0; ww < 8; ++ww) z += zred[ww][bb][ii];
        Zinv[((size_t)bb << 11) + i0 + ii] = 1.0f / z;
    }
}

// ---------------------------------------------------------------------------
// accum: s[b,j,:] += sum_i c[b,i,j] * u_hat[b,j,i,:]
// grid 512 = (j<<3)|iq; 512 thr = 8 waves; wave w owns i in [iq*256 + w*32, +32), all 32 b.
// MODE 0: c = 1/64. MODE 1: c = exp(veff.u)*Zinv.
// PREC 0: W hi-only (2 MFMAs). PREC 1: full hi/lo (3 MFMAs).
template<int MODE, int PREC>
__global__ __launch_bounds__(512, 2)
void accum_pass(const float* __restrict__ W, const float* __restrict__ x,
                const float* __restrict__ veff, const float* __restrict__ Zinv,
                float* __restrict__ sbuf)
{
    __shared__ float sred[8][32][36];         // [wave][b][m] (+4 pad)
    const int tid = threadIdx.x;
    const int l = tid & 63, w = tid >> 6;     // w = 0..7
    const int b = l & 31, h = l >> 5;
    const int j  = blockIdx.x >> 3;
    const int iq = blockIdx.x & 7;
    const int ibase = iq * 256 + w * 32;

    float4 vq0, vq1, vq2, vq3;
    if (MODE) {
        const float* vr = veff + ((((size_t)b << 6) | (size_t)j) << 5) + (h << 2);
        vq0 = *(const float4*)(vr + 0);
        vq1 = *(const float4*)(vr + 8);
        vq2 = *(const float4*)(vr + 16);
        vq3 = *(const float4*)(vr + 24);
    }
    f32x16 accs;
    #pragma unroll
    for (int r = 0; r < 16; ++r) accs[r] = 0.f;

    const float* wrow = W + (((size_t)j << 20) + ((size_t)ibase << 9) + (b << 4) + (h << 3));
    #pragma unroll 2
    for (int ii = 0; ii < 32; ++ii) {
        const int i = ibase + ii;
        const float* xr = x + (((size_t)b << 15) + ((size_t)i << 4) + (h << 3));
        bf16x8 xh, xl, wh, wl;
        cvt8(*(const float4*)xr, *(const float4*)(xr + 4), xh, xl);
        if (PREC) {
            cvt8(*(const float4*)wrow, *(const float4*)(wrow + 4), wh, wl);
        } else {
            wh = cvt8hi(*(const float4*)wrow, *(const float4*)(wrow + 4));
        }
        wrow += 512;
        if (MODE == 0) {
            accs = MFMA(wh, xh, accs);
            accs = MFMA(wh, xl, accs);
            if (PREC) accs = MFMA(wl, xh, accs);
        } else {
            f32x16 u;
            #pragma unroll
            for (int r = 0; r < 16; ++r) u[r] = 0.f;
            u = MFMA(wh, xh, u);
            u = MFMA(wh, xl, u);
            if (PREC) u = MFMA(wl, xh, u);
            float th = 0.f;
            th = fmaf(u[0],  vq0.x, th); th = fmaf(u[1],  vq0.y, th);
            th = fmaf(u[2],  vq0.z, th); th = fmaf(u[3],  vq0.w, th);
            th = fmaf(u[4],  vq1.x, th); th = fmaf(u[5],  vq1.y, th);
            th = fmaf(u[6],  vq1.z, th); th = fmaf(u[7],  vq1.w, th);
            th = fmaf(u[8],  vq2.x, th); th = fmaf(u[9],  vq2.y, th);
            th = fmaf(u[10], vq2.z, th); th = fmaf(u[11], vq2.w, th);
            th = fmaf(u[12], vq3.x, th); th = fmaf(u[13], vq3.y, th);
            th = fmaf(u[14], vq3.z, th); th = fmaf(u[15], vq3.w, th);
            const float t = th + __shfl_xor(th, 32, 64);
            const float c = __expf(t) * Zinv[((size_t)b << 11) + i];
            #pragma unroll
            for (int r = 0; r < 16; ++r) accs[r] = fmaf(c, u[r], accs[r]);
        }
    }
    const float scale = (MODE == 0) ? 0.015625f : 1.0f;
    #pragma unroll
    for (int q = 0; q < 4; ++q) {
        *(float4*)&sred[w][b][q * 8 + (h << 2)] =
            make_float4(accs[q*4] * scale, accs[q*4+1] * scale,
                        accs[q*4+2] * scale, accs[q*4+3] * scale);
    }
    __syncthreads();
    #pragma unroll
    for (int k = 0; k < 2; ++k) {
        const int idx = tid * 2 + k;
        const int bb = idx >> 5, mm = idx & 31;
        float s = 0.f;
        #pragma unroll
        for (int ww = 0; ww < 8; ++ww) s += sred[ww][bb][mm];
        atomicAdd(sbuf + ((((size_t)bb << 6) | (size_t)j) << 5) + mm, s);
    }
}

// ---------------------------------------------------------------------------
// squash: v = squash(s + bias) (+ vold); then zero sbuf for the next accum pass.
__global__ __launch_bounds__(256)
void squash_pass(float* __restrict__ sbuf, const float* __restrict__ bias,
                 float* __restrict__ vout, const float* __restrict__ vold)
{
    const int tid = threadIdx.x;
    const int m = tid & 31, g = tid >> 5;
    const int pair = blockIdx.x * 8 + g;      // b*64 + j
    const int j = pair & 63;
    const size_t idx = ((size_t)pair << 5) + m;
    float s = sbuf[idx] + bias[(j << 5) + m];
    sbuf[idx] = 0.f;                          // re-arm for next accum
    float n2 = s * s;
    n2 += __shfl_xor(n2, 1, 64);  n2 += __shfl_xor(n2, 2, 64);
    n2 += __shfl_xor(n2, 4, 64);  n2 += __shfl_xor(n2, 8, 64);
    n2 += __shfl_xor(n2, 16, 64);
    float v = s * (n2 / (1.f + n2)) / sqrtf(n2 + FEPS);
    if (vold) v += vold[idx];
    vout[idx] = v;
}

extern "C" void kernel_launch(void* const* d_in, const int* in_sizes, int n_in,
                              void* d_out, int out_size, void* d_ws, size_t ws_size,
                              hipStream_t stream)
{
    const float* x    = (const float*)d_in[0];
    const float* W    = (const float*)d_in[1];
    const float* bias = (const float*)d_in[2];
    float* out  = (float*)d_out;              // running veff lives here
    float* sbuf = (float*)d_ws;               // 65536 floats
    float* Zinv = sbuf + 65536;               // 65536 floats

    hipMemsetAsync(sbuf, 0, 65536 * sizeof(float), stream);

    // it0: c = 1/64 exactly -> out = v0          (PREC 0: routing-weight pass)
    accum_pass<0, 0><<<512, 512, 0, stream>>>(W, x, nullptr, nullptr, sbuf);
    squash_pass<<<256, 256, 0, stream>>>(sbuf, bias, out, nullptr);
    // it1: Z from veff=v0; out = v0 + v1         (PREC 0)
    stats_pass<<<512, 512, 0, stream>>>(W, x, out, Zinv);
    accum_pass<1, 0><<<512, 512, 0, stream>>>(W, x, out, Zinv, sbuf);
    squash_pass<<<256, 256, 0, stream>>>(sbuf, bias, out, out);
    // it2: Z from veff=v0+v1; out = v2 (final)   (PREC 1: output-critical pass)
    stats_pass<<<512, 512, 0, stream>>>(W, x, out, Zinv);
    accum_pass<1, 1><<<512, 512, 0, stream>>>(W, x, out, Zinv, sbuf);
    squash_pass<<<256, 256, 0, stream>>>(sbuf, bias, out, nullptr);
}

// Round 12
// 291.782 us; speedup vs baseline: 3.8630x; 1.0505x over previous
//
#include <hip/hip_runtime.h>

// Dims: x[b=32][i=2048][n=16], W[j=64][i=2048][m=32][n=16], bias[j=64][m=32], out v[b=32][j=64][m=32]
// MFMA shape 32x32x16: M=m(32), N=b(32), K=n(16).
//   stats: pure bf16 hi, 1 MFMA (validated r10/r11).
//   accum it0/it1 (PREC=0): W hi-only, 2 MFMAs; it2 (PREC=1): full hi/lo, 3 MFMAs (validated r11).
// A frag: lane l holds W[j,i, m=l&31, n=(l>>5)*8+e]; B frag: x[b=l&31, i, n=(l>>5)*8+e]
// C/D:    lane l, reg r = u_hat[b=l&31][m=(r&3)+8*(r>>2)+4*(l>>5)]   (m74/m101-verified)
// ws: sbuf[65536] + ZinvT[65536] (layout [i][b]) + veffT[65536] (layout [j][m][b]) = 768 KB
//     (768 KB proven safe in r1). Transposed layouts kill the b-strided 32-line gathers (r11 finding).
// Grid 512 = 2 blocks/CU, 512-thr blocks. No fused tails (r10 spill-cliff lesson).
constexpr float FEPS = 1e-8f;

typedef __attribute__((ext_vector_type(8)))  short bf16x8;
typedef __attribute__((ext_vector_type(16))) float f32x16;

__device__ __forceinline__ short bf16_rne(float f) {
    unsigned u = __float_as_uint(f);
    return (short)((u + 0x7FFFu + ((u >> 16) & 1u)) >> 16);
}
__device__ __forceinline__ float bf16_val(short h) {
    return __uint_as_float(((unsigned)(unsigned short)h) << 16);
}
__device__ __forceinline__ void cvt8(const float4 a, const float4 b, bf16x8& hi, bf16x8& lo) {
    float v[8] = {a.x, a.y, a.z, a.w, b.x, b.y, b.z, b.w};
    #pragma unroll
    for (int e = 0; e < 8; ++e) {
        const short hb = bf16_rne(v[e]);
        hi[e] = hb;
        lo[e] = bf16_rne(v[e] - bf16_val(hb));
    }
}
__device__ __forceinline__ bf16x8 cvt8hi(const float4 a, const float4 b) {
    float v[8] = {a.x, a.y, a.z, a.w, b.x, b.y, b.z, b.w};
    bf16x8 hi;
    #pragma unroll
    for (int e = 0; e < 8; ++e) hi[e] = bf16_rne(v[e]);
    return hi;
}
#define MFMA(A, B, C) __builtin_amdgcn_mfma_f32_32x32x16_bf16((A), (B), (C), 0, 0, 0)

// ---------------------------------------------------------------------------
// stats: ZinvT[i][b] = 1 / sum_j exp(veff[b,j,:] . u_hat_bf16[b,j,i,:])
// grid 512 = 4-i slab; 512 thr = 8 waves; wave w covers j in {w, w+8, .., w+56}, all 4 i.
// veff consumed via veffT[j][m][b] (coalesced dword loads; no 32-line gathers).
__global__ __launch_bounds__(512, 2)
void stats_pass(const float* __restrict__ W, const float* __restrict__ x,
                const float* __restrict__ veffT, float* __restrict__ ZinvT)
{
    __shared__ float zred[8][32][5];          // [wave][b][ii] (+1 pad)
    const int tid = threadIdx.x;
    const int l = tid & 63, w = tid >> 6;     // w = 0..7
    const int b = l & 31, h = l >> 5;
    const int i0 = blockIdx.x * 4;

    bf16x8 xh[4];
    #pragma unroll
    for (int ii = 0; ii < 4; ++ii) {
        const float* xr = x + (((size_t)b << 15) + ((size_t)(i0 + ii) << 4) + (h << 3));
        xh[ii] = cvt8hi(*(const float4*)xr, *(const float4*)(xr + 4));
    }
    float zacc[4] = {0.f, 0.f, 0.f, 0.f};

    #pragma unroll 1
    for (int jt = 0; jt < 8; ++jt) {
        const int j = w + (jt << 3);
        // vf[r] = veff[b, j, m(r)] with m(r) = (r&3) + 8*(r>>2) + 4h — coalesced via veffT
        float vf[16];
        #pragma unroll
        for (int r = 0; r < 16; ++r) {
            const int mr = (r & 3) + ((r >> 2) << 3) + (h << 2);
            vf[r] = veffT[(((size_t)(j << 5) + mr) << 5) + b];
        }
        const float* wrow = W + (((size_t)j << 20) + ((size_t)i0 << 9) + (b << 4) + (h << 3));
        #pragma unroll
        for (int ii = 0; ii < 4; ++ii) {
            const bf16x8 wh = cvt8hi(*(const float4*)wrow, *(const float4*)(wrow + 4));
            wrow += 512;
            f32x16 u;
            #pragma unroll
            for (int r = 0; r < 16; ++r) u[r] = 0.f;
            u = MFMA(wh, xh[ii], u);
            float th = 0.f;
            #pragma unroll
            for (int r = 0; r < 16; ++r) th = fmaf(u[r], vf[r], th);
            const float t = th + __shfl_xor(th, 32, 64);   // both m-halves
            zacc[ii] += __expf(t);
        }
    }
    if (h == 0) {
        #pragma unroll
        for (int ii = 0; ii < 4; ++ii) zred[w][b][ii] = zacc[ii];
    }
    __syncthreads();
    if (tid < 128) {
        const int bb = tid >> 2, ii = tid & 3;
        float z = 0.f;
        #pragma unroll
        for (int ww = 0; ww < 8; ++ww) z += zred[ww][bb][ii];
        ZinvT[((size_t)(i0 + ii) << 5) + bb] = 1.0f / z;
    }
}

// ---------------------------------------------------------------------------
// accum: s[b,j,:] += sum_i c[b,i,j] * u_hat[b,j,i,:]
// grid 512 = (j<<3)|iq; 512 thr = 8 waves; wave w owns i in [iq*256 + w*32, +32), all 32 b.
// MODE 0: c = 1/64. MODE 1: c = exp(veff.u)*ZinvT[i][b] (coalesced).
// PREC 0: W hi-only (2 MFMAs). PREC 1: full hi/lo (3 MFMAs).
template<int MODE, int PREC>
__global__ __launch_bounds__(512, 2)
void accum_pass(const float* __restrict__ W, const float* __restrict__ x,
                const float* __restrict__ veffT, const float* __restrict__ ZinvT,
                float* __restrict__ sbuf)
{
    __shared__ float sred[8][32][36];         // [wave][b][m] (+4 pad)
    const int tid = threadIdx.x;
    const int l = tid & 63, w = tid >> 6;     // w = 0..7
    const int b = l & 31, h = l >> 5;
    const int j  = blockIdx.x >> 3;
    const int iq = blockIdx.x & 7;
    const int ibase = iq * 256 + w * 32;

    float vf[16];
    if (MODE) {
        #pragma unroll
        for (int r = 0; r < 16; ++r) {
            const int mr = (r & 3) + ((r >> 2) << 3) + (h << 2);
            vf[r] = veffT[(((size_t)(j << 5) + mr) << 5) + b];
        }
    }
    f32x16 accs;
    #pragma unroll
    for (int r = 0; r < 16; ++r) accs[r] = 0.f;

    const float* wrow = W + (((size_t)j << 20) + ((size_t)ibase << 9) + (b << 4) + (h << 3));
    #pragma unroll 2
    for (int ii = 0; ii < 32; ++ii) {
        const int i = ibase + ii;
        const float* xr = x + (((size_t)b << 15) + ((size_t)i << 4) + (h << 3));
        bf16x8 xh, xl, wh, wl;
        cvt8(*(const float4*)xr, *(const float4*)(xr + 4), xh, xl);
        if (PREC) {
            cvt8(*(const float4*)wrow, *(const float4*)(wrow + 4), wh, wl);
        } else {
            wh = cvt8hi(*(const float4*)wrow, *(const float4*)(wrow + 4));
        }
        wrow += 512;
        if (MODE == 0) {
            accs = MFMA(wh, xh, accs);
            accs = MFMA(wh, xl, accs);
            if (PREC) accs = MFMA(wl, xh, accs);
        } else {
            f32x16 u;
            #pragma unroll
            for (int r = 0; r < 16; ++r) u[r] = 0.f;
            u = MFMA(wh, xh, u);
            u = MFMA(wh, xl, u);
            if (PREC) u = MFMA(wl, xh, u);
            float th = 0.f;
            #pragma unroll
            for (int r = 0; r < 16; ++r) th = fmaf(u[r], vf[r], th);
            const float t = th + __shfl_xor(th, 32, 64);
            const float c = __expf(t) * ZinvT[((size_t)i << 5) + b];
            #pragma unroll
            for (int r = 0; r < 16; ++r) accs[r] = fmaf(c, u[r], accs[r]);
        }
    }
    const float scale = (MODE == 0) ? 0.015625f : 1.0f;
    #pragma unroll
    for (int q = 0; q < 4; ++q) {
        *(float4*)&sred[w][b][q * 8 + (h << 2)] =
            make_float4(accs[q*4] * scale, accs[q*4+1] * scale,
                        accs[q*4+2] * scale, accs[q*4+3] * scale);
    }
    __syncthreads();
    #pragma unroll
    for (int k = 0; k < 2; ++k) {
        const int idx = tid * 2 + k;
        const int bb = idx >> 5, mm = idx & 31;
        float s = 0.f;
        #pragma unroll
        for (int ww = 0; ww < 8; ++ww) s += sred[ww][bb][mm];
        atomicAdd(sbuf + ((((size_t)bb << 6) | (size_t)j) << 5) + mm, s);
    }
}

// ---------------------------------------------------------------------------
// squash: v = squash(s + bias) (+ vold); writes out[b][j][m], optionally veffT[j][m][b];
// zeroes sbuf element it read (re-arm for next accum pass).
__global__ __launch_bounds__(256)
void squash_pass(float* __restrict__ sbuf, const float* __restrict__ bias,
                 float* __restrict__ vout, const float* __restrict__ vold,
                 float* __restrict__ veffT)
{
    const int tid = threadIdx.x;
    const int m = tid & 31, g = tid >> 5;
    const int pair = blockIdx.x * 8 + g;      // b*64 + j
    const int b = pair >> 6, j = pair & 63;
    const size_t idx = ((size_t)pair << 5) + m;
    float s = sbuf[idx] + bias[(j << 5) + m];
    sbuf[idx] = 0.f;                          // re-arm for next accum
    float n2 = s * s;
    n2 += __shfl_xor(n2, 1, 64);  n2 += __shfl_xor(n2, 2, 64);
    n2 += __shfl_xor(n2, 4, 64);  n2 += __shfl_xor(n2, 8, 64);
    n2 += __shfl_xor(n2, 16, 64);
    float v = s * (n2 / (1.f + n2)) / sqrtf(n2 + FEPS);
    if (vold) v += vold[idx];
    vout[idx] = v;
    if (veffT) veffT[(((size_t)(j << 5) + m) << 5) + b] = v;
}

extern "C" void kernel_launch(void* const* d_in, const int* in_sizes, int n_in,
                              void* d_out, int out_size, void* d_ws, size_t ws_size,
                              hipStream_t stream)
{
    const float* x    = (const float*)d_in[0];
    const float* W    = (const float*)d_in[1];
    const float* bias = (const float*)d_in[2];
    float* out   = (float*)d_out;             // running v (output layout)
    float* sbuf  = (float*)d_ws;              // 65536 floats
    float* ZinvT = sbuf + 65536;              // 65536 floats, [i][b]
    float* veffT = sbuf + 131072;             // 65536 floats, [j][m][b]

    hipMemsetAsync(sbuf, 0, 65536 * sizeof(float), stream);

    // it0: c = 1/64 exactly -> out = v0, veffT = v0            (PREC 0)
    accum_pass<0, 0><<<512, 512, 0, stream>>>(W, x, nullptr, nullptr, sbuf);
    squash_pass<<<256, 256, 0, stream>>>(sbuf, bias, out, nullptr, veffT);
    // it1: Z from veff=v0; out = veffT = v0 + v1               (PREC 0)
    stats_pass<<<512, 512, 0, stream>>>(W, x, veffT, ZinvT);
    accum_pass<1, 0><<<512, 512, 0, stream>>>(W, x, veffT, ZinvT, sbuf);
    squash_pass<<<256, 256, 0, stream>>>(sbuf, bias, out, out, veffT);
    // it2: Z from veff=v0+v1; out = v2 (final)                 (PREC 1)
    stats_pass<<<512, 512, 0, stream>>>(W, x, veffT, ZinvT);
    accum_pass<1, 1><<<512, 512, 0, stream>>>(W, x, veffT, ZinvT, sbuf);
    squash_pass<<<256, 256, 0, stream>>>(sbuf, bias, out, nullptr, nullptr);
}

// Round 13
// 251.455 us; speedup vs baseline: 4.4826x; 1.1604x over previous
//
#include <hip/hip_runtime.h>

// Dims: x[b=32][i=2048][n=16], W[j=64][i=2048][m=32][n=16], bias[j=64][m=32], out v[b=32][j=64][m=32]
// MFMA 32x32x16: M=m, N=b, K=n. stats: bf16-hi 1 MFMA; accum it0/it1 PREC0 2 MFMA; it2 PREC1 3 MFMA.
// A frag: lane l holds W[j,i, m=l&31, n=(l>>5)*8+e]; B frag: x[b=l&31, i, n=(l>>5)*8+e]
// C/D: lane l, reg r = u_hat[b=l&31][m=(r&3)+8*(r>>2)+4*(l>>5)]   (m74/m101-verified)
// ws: sbuf[64K] + ZinvT[64K][i][b] + veffT[64K][j][m][b] (+ xfragHi/Lo 4 MB when ws allows).
// xfrag kills the 32-line b-strided x gathers + per-iter x cvt VALU (r12 finding, same as Zinv fix).
// Grid 512 = 2 blocks/CU, 512-thr blocks. No fused tails (r10 spill-cliff lesson).
constexpr float FEPS = 1e-8f;

typedef __attribute__((ext_vector_type(8)))  short bf16x8;
typedef __attribute__((ext_vector_type(16))) float f32x16;

__device__ __forceinline__ short bf16_rne(float f) {
    unsigned u = __float_as_uint(f);
    return (short)((u + 0x7FFFu + ((u >> 16) & 1u)) >> 16);
}
__device__ __forceinline__ float bf16_val(short h) {
    return __uint_as_float(((unsigned)(unsigned short)h) << 16);
}
__device__ __forceinline__ void cvt8(const float4 a, const float4 b, bf16x8& hi, bf16x8& lo) {
    float v[8] = {a.x, a.y, a.z, a.w, b.x, b.y, b.z, b.w};
    #pragma unroll
    for (int e = 0; e < 8; ++e) {
        const short hb = bf16_rne(v[e]);
        hi[e] = hb;
        lo[e] = bf16_rne(v[e] - bf16_val(hb));
    }
}
__device__ __forceinline__ bf16x8 cvt8hi(const float4 a, const float4 b) {
    float v[8] = {a.x, a.y, a.z, a.w, b.x, b.y, b.z, b.w};
    bf16x8 hi;
    #pragma unroll
    for (int e = 0; e < 8; ++e) hi[e] = bf16_rne(v[e]);
    return hi;
}
#define MFMA(A, B, C) __builtin_amdgcn_mfma_f32_32x32x16_bf16((A), (B), (C), 0, 0, 0)

// ---------------------------------------------------------------------------
// xprep: B-fragments for all i. xfH/xfL[i*64 + l] = lane-l bf16x8 of x[b=l&31, i, n=(l>>5)*8..]
__global__ __launch_bounds__(512)
void xprep(const float* __restrict__ x, bf16x8* __restrict__ xfH, bf16x8* __restrict__ xfL)
{
    const int tid = threadIdx.x;
    const int l = tid & 63, w = tid >> 6;
    const int b = l & 31, h = l >> 5;
    const int i = blockIdx.x * 8 + w;
    const float* xr = x + (((size_t)b << 15) + ((size_t)i << 4) + (h << 3));
    bf16x8 hi, lo;
    cvt8(*(const float4*)xr, *(const float4*)(xr + 4), hi, lo);
    xfH[((size_t)i << 6) + l] = hi;
    xfL[((size_t)i << 6) + l] = lo;
}

// ---------------------------------------------------------------------------
// stats: ZinvT[i][b] = 1 / sum_j exp(veff . u_hat_bf16)
// grid 512 = 4-i slab; 8 waves; wave w covers j in {w, w+8, ..}; veff via veffT[j][m][b].
template<int XF>
__global__ __launch_bounds__(512, 2)
void stats_pass(const float* __restrict__ W, const float* __restrict__ x,
                const float* __restrict__ veffT, float* __restrict__ ZinvT,
                const bf16x8* __restrict__ xfH)
{
    __shared__ float zred[8][32][5];
    const int tid = threadIdx.x;
    const int l = tid & 63, w = tid >> 6;
    const int b = l & 31, h = l >> 5;
    const int i0 = blockIdx.x * 4;

    bf16x8 xh[4];
    #pragma unroll
    for (int ii = 0; ii < 4; ++ii) {
        if (XF) {
            xh[ii] = xfH[((size_t)(i0 + ii) << 6) + l];
        } else {
            const float* xr = x + (((size_t)b << 15) + ((size_t)(i0 + ii) << 4) + (h << 3));
            xh[ii] = cvt8hi(*(const float4*)xr, *(const float4*)(xr + 4));
        }
    }
    float zacc[4] = {0.f, 0.f, 0.f, 0.f};

    #pragma unroll 1
    for (int jt = 0; jt < 8; ++jt) {
        const int j = w + (jt << 3);
        float vf[16];
        #pragma unroll
        for (int r = 0; r < 16; ++r) {
            const int mr = (r & 3) + ((r >> 2) << 3) + (h << 2);
            vf[r] = veffT[(((size_t)(j << 5) + mr) << 5) + b];
        }
        const float* wrow = W + (((size_t)j << 20) + ((size_t)i0 << 9) + (b << 4) + (h << 3));
        #pragma unroll
        for (int ii = 0; ii < 4; ++ii) {
            const bf16x8 wh = cvt8hi(*(const float4*)wrow, *(const float4*)(wrow + 4));
            wrow += 512;
            f32x16 u;
            #pragma unroll
            for (int r = 0; r < 16; ++r) u[r] = 0.f;
            u = MFMA(wh, xh[ii], u);
            float th = 0.f;
            #pragma unroll
            for (int r = 0; r < 16; ++r) th = fmaf(u[r], vf[r], th);
            const float t = th + __shfl_xor(th, 32, 64);
            zacc[ii] += __expf(t);
        }
    }
    if (h == 0) {
        #pragma unroll
        for (int ii = 0; ii < 4; ++ii) zred[w][b][ii] = zacc[ii];
    }
    __syncthreads();
    if (tid < 128) {
        const int bb = tid >> 2, ii = tid & 3;
        float z = 0.f;
        #pragma unroll
        for (int ww = 0; ww < 8; ++ww) z += zred[ww][bb][ii];
        ZinvT[((size_t)(i0 + ii) << 5) + bb] = 1.0f / z;
    }
}

// ---------------------------------------------------------------------------
// accum: s[b,j,:] += sum_i c * u_hat. grid 512 = (j<<3)|iq; wave w owns 32 i's.
// MODE 0: c=1/64. MODE 1: c=exp(veff.u)*ZinvT[i][b]. PREC 0: 2 MFMA. PREC 1: 3 MFMA.
template<int MODE, int PREC, int XF>
__global__ __launch_bounds__(512, 2)
void accum_pass(const float* __restrict__ W, const float* __restrict__ x,
                const float* __restrict__ veffT, const float* __restrict__ ZinvT,
                float* __restrict__ sbuf,
                const bf16x8* __restrict__ xfH, const bf16x8* __restrict__ xfL)
{
    __shared__ float sred[8][32][36];
    const int tid = threadIdx.x;
    const int l = tid & 63, w = tid >> 6;
    const int b = l & 31, h = l >> 5;
    const int j  = blockIdx.x >> 3;
    const int iq = blockIdx.x & 7;
    const int ibase = iq * 256 + w * 32;

    float vf[16];
    if (MODE) {
        #pragma unroll
        for (int r = 0; r < 16; ++r) {
            const int mr = (r & 3) + ((r >> 2) << 3) + (h << 2);
            vf[r] = veffT[(((size_t)(j << 5) + mr) << 5) + b];
        }
    }
    f32x16 accs;
    #pragma unroll
    for (int r = 0; r < 16; ++r) accs[r] = 0.f;

    const float* wrow = W + (((size_t)j << 20) + ((size_t)ibase << 9) + (b << 4) + (h << 3));
    #pragma unroll 2
    for (int ii = 0; ii < 32; ++ii) {
        const int i = ibase + ii;
        bf16x8 xh, xl, wh, wl;
        if (XF) {
            xh = xfH[((size_t)i << 6) + l];
            xl = xfL[((size_t)i << 6) + l];
        } else {
            const float* xr = x + (((size_t)b << 15) + ((size_t)i << 4) + (h << 3));
            cvt8(*(const float4*)xr, *(const float4*)(xr + 4), xh, xl);
        }
        if (PREC) {
            cvt8(*(const float4*)wrow, *(const float4*)(wrow + 4), wh, wl);
        } else {
            wh = cvt8hi(*(const float4*)wrow, *(const float4*)(wrow + 4));
        }
        wrow += 512;
        if (MODE == 0) {
            accs = MFMA(wh, xh, accs);
            accs = MFMA(wh, xl, accs);
            if (PREC) accs = MFMA(wl, xh, accs);
        } else {
            f32x16 u;
            #pragma unroll
            for (int r = 0; r < 16; ++r) u[r] = 0.f;
            u = MFMA(wh, xh, u);
            u = MFMA(wh, xl, u);
            if (PREC) u = MFMA(wl, xh, u);
            float th = 0.f;
            #pragma unroll
            for (int r = 0; r < 16; ++r) th = fmaf(u[r], vf[r], th);
            const float t = th + __shfl_xor(th, 32, 64);
            const float c = __expf(t) * ZinvT[((size_t)i << 5) + b];
            #pragma unroll
            for (int r = 0; r < 16; ++r) accs[r] = fmaf(c, u[r], accs[r]);
        }
    }
    const float scale = (MODE == 0) ? 0.015625f : 1.0f;
    #pragma unroll
    for (int q = 0; q < 4; ++q) {
        *(float4*)&sred[w][b][q * 8 + (h << 2)] =
            make_float4(accs[q*4] * scale, accs[q*4+1] * scale,
                        accs[q*4+2] * scale, accs[q*4+3] * scale);
    }
    __syncthreads();
    #pragma unroll
    for (int k = 0; k < 2; ++k) {
        const int idx = tid * 2 + k;
        const int bb = idx >> 5, mm = idx & 31;
        float s = 0.f;
        #pragma unroll
        for (int ww = 0; ww < 8; ++ww) s += sred[ww][bb][mm];
        atomicAdd(sbuf + ((((size_t)bb << 6) | (size_t)j) << 5) + mm, s);
    }
}

// ---------------------------------------------------------------------------
// squash: v = squash(s + bias) (+ vold); writes out and optionally veffT; re-arms sbuf.
__global__ __launch_bounds__(256)
void squash_pass(float* __restrict__ sbuf, const float* __restrict__ bias,
                 float* __restrict__ vout, const float* __restrict__ vold,
                 float* __restrict__ veffT)
{
    const int tid = threadIdx.x;
    const int m = tid & 31, g = tid >> 5;
    const int pair = blockIdx.x * 8 + g;      // b*64 + j
    const int b = pair >> 6, j = pair & 63;
    const size_t idx = ((size_t)pair << 5) + m;
    float s = sbuf[idx] + bias[(j << 5) + m];
    sbuf[idx] = 0.f;
    float n2 = s * s;
    n2 += __shfl_xor(n2, 1, 64);  n2 += __shfl_xor(n2, 2, 64);
    n2 += __shfl_xor(n2, 4, 64);  n2 += __shfl_xor(n2, 8, 64);
    n2 += __shfl_xor(n2, 16, 64);
    float v = s * (n2 / (1.f + n2)) / sqrtf(n2 + FEPS);
    if (vold) v += vold[idx];
    vout[idx] = v;
    if (veffT) veffT[(((size_t)(j << 5) + m) << 5) + b] = v;
}

extern "C" void kernel_launch(void* const* d_in, const int* in_sizes, int n_in,
                              void* d_out, int out_size, void* d_ws, size_t ws_size,
                              hipStream_t stream)
{
    const float* x    = (const float*)d_in[0];
    const float* W    = (const float*)d_in[1];
    const float* bias = (const float*)d_in[2];
    float* out   = (float*)d_out;
    float* sbuf  = (float*)d_ws;              // 65536 floats
    float* ZinvT = sbuf + 65536;              // [i][b]
    float* veffT = sbuf + 131072;             // [j][m][b]
    bf16x8* xfH  = (bf16x8*)(sbuf + 196608);  // 131072 frags = 2 MB
    bf16x8* xfL  = xfH + 131072;              // 2 MB

    const bool xf = ws_size >= (size_t)(196608 + 2 * 131072 * 4) * sizeof(float); // 4.75 MB

    hipMemsetAsync(sbuf, 0, 65536 * sizeof(float), stream);

    if (xf) {
        xprep<<<256, 512, 0, stream>>>(x, xfH, xfL);
        accum_pass<0, 0, 1><<<512, 512, 0, stream>>>(W, x, nullptr, nullptr, sbuf, xfH, xfL);
        squash_pass<<<256, 256, 0, stream>>>(sbuf, bias, out, nullptr, veffT);
        stats_pass<1><<<512, 512, 0, stream>>>(W, x, veffT, ZinvT, xfH);
        accum_pass<1, 0, 1><<<512, 512, 0, stream>>>(W, x, veffT, ZinvT, sbuf, xfH, xfL);
        squash_pass<<<256, 256, 0, stream>>>(sbuf, bias, out, out, veffT);
        stats_pass<1><<<512, 512, 0, stream>>>(W, x, veffT, ZinvT, xfH);
        accum_pass<1, 1, 1><<<512, 512, 0, stream>>>(W, x, veffT, ZinvT, sbuf, xfH, xfL);
        squash_pass<<<256, 256, 0, stream>>>(sbuf, bias, out, nullptr, nullptr);
    } else {
        // exact r12 path (291.8 us proven)
        accum_pass<0, 0, 0><<<512, 512, 0, stream>>>(W, x, nullptr, nullptr, sbuf, nullptr, nullptr);
        squash_pass<<<256, 256, 0, stream>>>(sbuf, bias, out, nullptr, veffT);
        stats_pass<0><<<512, 512, 0, stream>>>(W, x, veffT, ZinvT, nullptr);
        accum_pass<1, 0, 0><<<512, 512, 0, stream>>>(W, x, veffT, ZinvT, sbuf, nullptr, nullptr);
        squash_pass<<<256, 256, 0, stream>>>(sbuf, bias, out, out, veffT);
        stats_pass<0><<<512, 512, 0, stream>>>(W, x, veffT, ZinvT, nullptr);
        accum_pass<1, 1, 0><<<512, 512, 0, stream>>>(W, x, veffT, ZinvT, sbuf, nullptr, nullptr);
        squash_pass<<<256, 256, 0, stream>>>(sbuf, bias, out, nullptr, nullptr);
    }
}